// Round 6
// baseline (215.804 us; speedup 1.0000x reference)
//
#include <hip/hip_runtime.h>
#include <hip/hip_bf16.h>

// partial row layout (12 floats, 3 x float4):
//   [0]=cls [1]=noobj [2]=S0 [3]=S1_p0 [4]=S2_p0 [5]=S1_p1 [6]=S2_p1
//   [7]=reg_p0 [8]=reg_p1 [9]=imax (int bitcast) [10..11] pad
#define NQ   9
#define ROW  12

// Single-pass cell-PAIR kernel. A pair (2 cells) = 240 B of pred (15 aligned
// float4), 160 B of tcls (10 aligned float4), 32 B tbox (2 float4), 8 B obj
// (int2). All 28 loads per pair are independent -> deep MLP per wave.
// Every input line is touched exactly once. No LDS/barriers in the hot loop.
__global__ __launch_bounds__(256, 4) void yolo_partial_kernel(
    const float* __restrict__ pred,
    const float* __restrict__ tbox,
    const float* __restrict__ tcls,
    const int*   __restrict__ obj,
    float* __restrict__ partial,     // [gridDim.x * ROW]
    int M)
{
    const int t        = threadIdx.x;
    const int gtid     = blockIdx.x * 256 + t;
    const int nthreads = gridDim.x * 256;
    const int npairs   = M >> 1;

    float acc[NQ];
#pragma unroll
    for (int q = 0; q < NQ; ++q) acc[q] = 0.f;
    int imax = -1;

    for (int p = gtid; p < npairs; p += nthreads) {
        // ---- issue all 28 independent loads ----
        const float4* pv = reinterpret_cast<const float4*>(pred) + (size_t)p * 15;
        const float4* cv = reinterpret_cast<const float4*>(tcls) + (size_t)p * 10;
        const float4* bv = reinterpret_cast<const float4*>(tbox) + (size_t)p * 2;
        const int2    oo = reinterpret_cast<const int2*>(obj)[p];
        const float4  tb0 = bv[0];
        const float4  tb1 = bv[1];

        float pr[60];
#pragma unroll
        for (int j = 0; j < 15; ++j) {
            float4 v = pv[j];
            pr[4 * j + 0] = v.x; pr[4 * j + 1] = v.y;
            pr[4 * j + 2] = v.z; pr[4 * j + 3] = v.w;
        }
        float tc[40];
#pragma unroll
        for (int j = 0; j < 10; ++j) {
            float4 v = cv[j];
            tc[4 * j + 0] = v.x; tc[4 * j + 1] = v.y;
            tc[4 * j + 2] = v.z; tc[4 * j + 3] = v.w;
        }

        // ---- cls loss for both cells ----
        float cl = 0.f;
#pragma unroll
        for (int k = 0; k < 20; ++k) {
            float d0 = pr[10 + k] - tc[k];
            float d1 = pr[40 + k] - tc[20 + k];
            cl += d0 * d0 + d1 * d1;
        }
        acc[0] += cl;

        // ---- per-cell terms: cell A (pr[0..9]) ----
        {
            const float p0c = pr[4];
            if (!oo.x) {
                acc[1] += p0c * p0c;             // L_NOOBJ * 2 == 1.0
            } else {
                acc[2] += 1.f;
                acc[3] += p0c;
                acc[4] += p0c * p0c;
                const float p1c = pr[9];
                acc[5] += p1c;
                acc[6] += p1c * p1c;
                const float st2 = sqrtf(tb0.z), st3 = sqrtf(tb0.w);
                float dx = pr[0] - tb0.x, dy = pr[1] - tb0.y;
                float dw = sqrtf(pr[2]) - st2, dh = sqrtf(pr[3]) - st3;
                acc[7] += dx * dx + dy * dy + dw * dw + dh * dh;
                dx = pr[5] - tb0.x; dy = pr[6] - tb0.y;
                dw = sqrtf(pr[7]) - st2; dh = sqrtf(pr[8]) - st3;
                acc[8] += dx * dx + dy * dy + dw * dw + dh * dh;
                imax = max(imax, 2 * p);
            }
        }
        // ---- per-cell terms: cell B (pr[30..39]) ----
        {
            const float p0c = pr[34];
            if (!oo.y) {
                acc[1] += p0c * p0c;
            } else {
                acc[2] += 1.f;
                acc[3] += p0c;
                acc[4] += p0c * p0c;
                const float p1c = pr[39];
                acc[5] += p1c;
                acc[6] += p1c * p1c;
                const float st2 = sqrtf(tb1.z), st3 = sqrtf(tb1.w);
                float dx = pr[30] - tb1.x, dy = pr[31] - tb1.y;
                float dw = sqrtf(pr[32]) - st2, dh = sqrtf(pr[33]) - st3;
                acc[7] += dx * dx + dy * dy + dw * dw + dh * dh;
                dx = pr[35] - tb1.x; dy = pr[36] - tb1.y;
                dw = sqrtf(pr[37]) - st2; dh = sqrtf(pr[38]) - st3;
                acc[8] += dx * dx + dy * dy + dw * dw + dh * dh;
                imax = max(imax, 2 * p + 1);
            }
        }
    }

    // odd trailing cell (M odd), handled by one thread
    if ((M & 1) && gtid == 0) {
        const int c = M - 1;
        const float* s = pred + (size_t)c * 30;
        const float* tcp = tcls + (size_t)c * 20;
        float cl = 0.f;
        for (int k = 0; k < 20; ++k) { float d = s[10 + k] - tcp[k]; cl += d * d; }
        acc[0] += cl;
        const float p0c = s[4];
        if (!obj[c]) acc[1] += p0c * p0c;
        else {
            const float* tb = tbox + (size_t)c * 4;
            acc[2] += 1.f; acc[3] += p0c; acc[4] += p0c * p0c;
            const float p1c = s[9];
            acc[5] += p1c; acc[6] += p1c * p1c;
            const float st2 = sqrtf(tb[2]), st3 = sqrtf(tb[3]);
            float dx = s[0] - tb[0], dy = s[1] - tb[1];
            float dw = sqrtf(s[2]) - st2, dh = sqrtf(s[3]) - st3;
            acc[7] += dx * dx + dy * dy + dw * dw + dh * dh;
            dx = s[5] - tb[0]; dy = s[6] - tb[1];
            dw = sqrtf(s[7]) - st2; dh = sqrtf(s[8]) - st3;
            acc[8] += dx * dx + dy * dy + dw * dw + dh * dh;
            imax = max(imax, c);
        }
    }

    // ---- wave (64-lane) shuffle reduction ----
#pragma unroll
    for (int off = 32; off > 0; off >>= 1) {
#pragma unroll
        for (int q = 0; q < NQ; ++q) acc[q] += __shfl_down(acc[q], off, 64);
        imax = max(imax, __shfl_down(imax, off, 64));
    }

    __shared__ float sred[4][NQ];
    __shared__ int   sidx[4];
    const int lane = t & 63;
    const int wid  = t >> 6;
    if (lane == 0) {
#pragma unroll
        for (int q = 0; q < NQ; ++q) sred[wid][q] = acc[q];
        sidx[wid] = imax;
    }
    __syncthreads();

    if (t == 0) {
        float tot[NQ];
        int   mx = sidx[0];
#pragma unroll
        for (int q = 0; q < NQ; ++q) tot[q] = sred[0][q];
        for (int w = 1; w < 4; ++w) {
#pragma unroll
            for (int q = 0; q < NQ; ++q) tot[q] += sred[w][q];
            mx = max(mx, sidx[w]);
        }
        float4* row = reinterpret_cast<float4*>(partial + (size_t)blockIdx.x * ROW);
        row[0] = make_float4(tot[0], tot[1], tot[2], tot[3]);
        row[1] = make_float4(tot[4], tot[5], tot[6], tot[7]);
        row[2] = make_float4(tot[8], __int_as_float(mx), 0.f, 0.f);
    }
}

__global__ __launch_bounds__(256) void yolo_final_kernel(
    const float* __restrict__ pred,
    const float* __restrict__ tbox,
    const float* __restrict__ partial,
    float* __restrict__ out,
    int nrows, float invN)
{
    const int t = threadIdx.x;
    float acc[NQ];
#pragma unroll
    for (int q = 0; q < NQ; ++q) acc[q] = 0.f;
    int imax = -1;

    for (int r = t; r < nrows; r += 256) {
        const float4* row = reinterpret_cast<const float4*>(partial + (size_t)r * ROW);
        float4 a = row[0], b = row[1], c = row[2];
        acc[0] += a.x; acc[1] += a.y; acc[2] += a.z; acc[3] += a.w;
        acc[4] += b.x; acc[5] += b.y; acc[6] += b.z; acc[7] += b.w;
        acc[8] += c.x;
        imax = max(imax, __float_as_int(c.y));
    }

#pragma unroll
    for (int off = 32; off > 0; off >>= 1) {
#pragma unroll
        for (int q = 0; q < NQ; ++q) acc[q] += __shfl_down(acc[q], off, 64);
        imax = max(imax, __shfl_down(imax, off, 64));
    }

    __shared__ float sred[4][NQ];
    __shared__ int   sidx[4];
    const int lane = t & 63;
    const int wid  = t >> 6;
    if (lane == 0) {
#pragma unroll
        for (int q = 0; q < NQ; ++q) sred[wid][q] = acc[q];
        sidx[wid] = imax;
    }
    __syncthreads();

    if (t == 0) {
        float sums[NQ];
        int idx = sidx[0];
#pragma unroll
        for (int q = 0; q < NQ; ++q) sums[q] = sred[0][q];
        for (int w = 1; w < 4; ++w) {
#pragma unroll
            for (int q = 0; q < NQ; ++q) sums[q] += sred[w][q];
            idx = max(idx, sidx[w]);
        }

        const float* p  = pred + (size_t)idx * 30;
        const float* tb = tbox + (size_t)idx * 4;

        float b0[4], b1[4], bt[4];
        {
            float cx = p[0] / 14.f, cy = p[1] / 14.f;
            b0[0] = cx - 0.5f * p[2]; b0[1] = cy - 0.5f * p[3];
            b0[2] = cx + 0.5f * p[2]; b0[3] = cy + 0.5f * p[3];
        }
        {
            float cx = p[5] / 14.f, cy = p[6] / 14.f;
            b1[0] = cx - 0.5f * p[7]; b1[1] = cy - 0.5f * p[8];
            b1[2] = cx + 0.5f * p[7]; b1[3] = cy + 0.5f * p[8];
        }
        {
            float cx = tb[0] / 14.f, cy = tb[1] / 14.f;
            bt[0] = cx - 0.5f * tb[2]; bt[1] = cy - 0.5f * tb[3];
            bt[2] = cx + 0.5f * tb[2]; bt[3] = cy + 0.5f * tb[3];
        }
        auto iou = [](const float* a, const float* b) {
            float ltx = fmaxf(a[0], b[0]), lty = fmaxf(a[1], b[1]);
            float rbx = fminf(a[2], b[2]), rby = fminf(a[3], b[3]);
            float w = fmaxf(rbx - ltx, 0.f), h = fmaxf(rby - lty, 0.f);
            float inter = w * h;
            float a1 = (a[2] - a[0]) * (a[3] - a[1]);
            float a2 = (b[2] - b[0]) * (b[3] - b[1]);
            return inter / (a1 + a2 - inter);
        };
        float iou0 = iou(b0, bt), iou1 = iou(b1, bt);
        bool  m = iou0 > iou1;
        float c = m ? iou0 : iou1;

        float S0  = sums[2];
        float S1  = m ? sums[3] : sums[5];
        float S2  = m ? sums[4] : sums[6];
        float reg = m ? sums[7] : sums[8];

        float reg_loss   = 5.f * reg;                       // L_COORD
        float containing = S2 - 2.f * c * S1 + c * c * S0;  // sum obj*(conf-c)^2
        float noobj      = sums[1];
        float cls        = sums[0];
        float total      = cls + noobj + reg_loss + containing;

        out[0] = total * invN;
        out[1] = reg_loss * invN;
        out[2] = containing * invN;
        out[3] = noobj * invN;
        out[4] = cls * invN;
    }
}

extern "C" void kernel_launch(void* const* d_in, const int* in_sizes, int n_in,
                              void* d_out, int out_size, void* d_ws, size_t ws_size,
                              hipStream_t stream) {
    const float* pred = (const float*)d_in[0];
    const float* tbox = (const float*)d_in[1];
    const float* tcls = (const float*)d_in[2];
    const int*   obj  = (const int*)d_in[3];
    float* out = (float*)d_out;

    const int M = in_sizes[3];                  // BATCH * S * S
    const int N = in_sizes[0] / (14 * 14 * 30); // BATCH

    // 784 blocks: exactly 2 pairs/thread at M=802816; ~3 blocks/CU resident
    int nblk = 784;
    const int max_rows = (int)(ws_size / (ROW * sizeof(float)));
    if (nblk > max_rows) nblk = max_rows;
    if (nblk < 1) nblk = 1;

    float* partial = (float*)d_ws;

    yolo_partial_kernel<<<nblk, 256, 0, stream>>>(pred, tbox, tcls, obj, partial, M);
    yolo_final_kernel<<<1, 256, 0, stream>>>(pred, tbox, partial, out, nblk, 1.f / (float)N);
}